// Round 7
// baseline (394.691 us; speedup 1.0000x reference)
//
#include <hip/hip_runtime.h>
#include <math.h>

#define BB   64
#define NTOK 197
#define CC   768
#define HH   12
#define DH   64
#define MTOT (BB * NTOK)          // 12608
#define MPAD 12672                // 99*128
#define LEFT 138

// d_out layout (floats, concatenated in return order)
#define XOUT_OFF  0
#define INDEX_OFF 9682944         // B*N*C
#define IDX_OFF   16465920        // + B*138*C
#define CLS_OFF   16474752        // + B*138
#define LT_OFF    16487296        // + B*196

typedef short s8v __attribute__((ext_vector_type(8)));
typedef short s4v __attribute__((ext_vector_type(4)));
typedef float f4v __attribute__((ext_vector_type(4)));

#define GLOAD16(g, l) __builtin_amdgcn_global_load_lds( \
    (const __attribute__((address_space(1))) unsigned int*)(g), \
    (__attribute__((address_space(3))) unsigned int*)(l), 16, 0, 0)

__device__ __forceinline__ unsigned short f2bf(float f) {
    union { float f; unsigned int i; } x; x.f = f;
    unsigned int r = x.i + 0x7FFFu + ((x.i >> 16) & 1u);   // RNE
    return (unsigned short)(r >> 16);
}

// ---------------------------------------------------------------------------
// prep: fused convert_x (blocks [0,4728)) + transpose qkv_w ([4728,6456))
// + transpose proj_w ([6456,7032)). Block-uniform branch.
// ---------------------------------------------------------------------------
__global__ __launch_bounds__(256)
void prep(const float* __restrict__ x, const float* __restrict__ qkv_w,
          const float* __restrict__ proj_w, unsigned short* __restrict__ xbf,
          unsigned short* __restrict__ wt1, unsigned short* __restrict__ wt2)
{
    const int id = blockIdx.x;
    if (id < 4728) {
        size_t i = ((size_t)id * 256 + threadIdx.x) * 8;
        float4 a = *(const float4*)(x + i);
        float4 b = *(const float4*)(x + i + 4);
        s8v r;
        r[0] = (short)f2bf(a.x); r[1] = (short)f2bf(a.y);
        r[2] = (short)f2bf(a.z); r[3] = (short)f2bf(a.w);
        r[4] = (short)f2bf(b.x); r[5] = (short)f2bf(b.y);
        r[6] = (short)f2bf(b.z); r[7] = (short)f2bf(b.w);
        *(s8v*)(xbf + i) = r;
        return;
    }
    __shared__ float tile[32][33];
    const float* in;
    unsigned short* outt;
    int N, bi, bj;
    if (id < 6456) {
        int t = id - 4728; in = qkv_w; outt = wt1; N = 2304;
        bi = t % 24; bj = t / 24;               // bi over K/32, bj over N/32
    } else {
        int t = id - 6456; in = proj_w; outt = wt2; N = 768;
        bi = t % 24; bj = t / 24;
    }
    const int tx = threadIdx.x & 31, ty = threadIdx.x >> 5;
#pragma unroll
    for (int r = ty; r < 32; r += 8)
        tile[r][tx] = in[(size_t)(bi * 32 + r) * N + bj * 32 + tx];
    __syncthreads();
#pragma unroll
    for (int r = ty; r < 32; r += 8)
        outt[(size_t)(bj * 32 + r) * 768 + bi * 32 + tx] = f2bf(tile[tx][r]);
}

// ---------------------------------------------------------------------------
// bf16 MFMA GEMM, single-barrier double-buffered prefetch: tile k+1's
// global_load_lds issues right after the barrier, overlapping compute on
// tile k; the next barrier's vmcnt(0) drain then finds the loads landed.
// XOR-swizzled LDS, swapped operands for column-vectorized epilogue.
// ---------------------------------------------------------------------------
__global__ __launch_bounds__(256)
void gemm_bf16(const unsigned short* __restrict__ A, const unsigned short* __restrict__ BT,
               const float* __restrict__ bias, int ncolt, int mode,
               unsigned short* __restrict__ outb, float* __restrict__ outf)
{
    const int id = blockIdx.x;
    const int xcd = id & 7;
    const int t = id >> 3;
    const int ct = t % ncolt, s = t / ncolt;
    const int rt = s * 8 + xcd;
    if (rt >= 99) return;
    const int m0 = rt * 128, n0 = ct * 128;

    const int tid = threadIdx.x;
    const int wave = tid >> 6, lane = tid & 63;
    const int quad = lane >> 4, l16 = lane & 15;
    const int rowbase = (wave >> 1) * 64, colbase = (wave & 1) * 64;
    __shared__ __align__(16) short As[2 * 8192];   // 2 x 16KB
    __shared__ __align__(16) short Bs[2 * 8192];

    const int rA   = lane >> 3;
    const int gcol = ((lane & 7) ^ rA) * 8;
    const unsigned short* gA[4];
    const unsigned short* gB[4];
    int ldsoff[4];
#pragma unroll
    for (int i = 0; i < 4; ++i) {
        int c = wave * 4 + i;
        gA[i] = A  + (size_t)(m0 + c * 8 + rA) * 768 + gcol;
        gB[i] = BT + (size_t)(n0 + c * 8 + rA) * 768 + gcol;
        ldsoff[i] = c * 512;                    // + lane*8 applied by HW
    }
    int aoff[4], boff[4];
#pragma unroll
    for (int i = 0; i < 4; ++i) {
        aoff[i] = (rowbase + i * 16 + l16) * 64 + ((quad ^ (l16 & 7)) * 8);
        boff[i] = (colbase + i * 16 + l16) * 64 + ((quad ^ (l16 & 7)) * 8);
    }

    f4v acc[4][4];
#pragma unroll
    for (int i = 0; i < 4; ++i)
#pragma unroll
        for (int j = 0; j < 4; ++j) acc[i][j] = (f4v)0.f;

    // prologue: loads for k-tile 0 into buffer 0
#pragma unroll
    for (int i = 0; i < 4; ++i) {
        GLOAD16(gA[i], &As[ldsoff[i]]);
        GLOAD16(gB[i], &Bs[ldsoff[i]]);
    }

    for (int it = 0; it < 12; ++it) {
        __syncthreads();                        // buf[it&1] ready; prev reads done
        if (it < 11) {
            const int k0 = (it + 1) * 64;
            const int bo = ((it + 1) & 1) * 8192;
#pragma unroll
            for (int i = 0; i < 4; ++i) {
                GLOAD16(gA[i] + k0, &As[bo + ldsoff[i]]);
                GLOAD16(gB[i] + k0, &Bs[bo + ldsoff[i]]);
            }
        }
        const short* curA = &As[(it & 1) * 8192];
        const short* curB = &Bs[(it & 1) * 8192];
#pragma unroll
        for (int ks = 0; ks < 2; ++ks) {
            const int x = ks * 32;
            s8v af[4], bf[4];
#pragma unroll
            for (int i = 0; i < 4; ++i) af[i] = *(const s8v*)&curA[aoff[i] ^ x];
#pragma unroll
            for (int j = 0; j < 4; ++j) bf[j] = *(const s8v*)&curB[boff[j] ^ x];
#pragma unroll
            for (int i = 0; i < 4; ++i)
#pragma unroll
                for (int j = 0; j < 4; ++j)
                    acc[i][j] = __builtin_amdgcn_mfma_f32_16x16x32_bf16(bf[j], af[i], acc[i][j], 0, 0, 0);
        }
    }

    const int ncols = mode ? 768 : 2304;
#pragma unroll
    for (int i = 0; i < 4; ++i) {
        const int m = m0 + rowbase + i * 16 + l16;
        if (m >= MTOT) continue;
#pragma unroll
        for (int j = 0; j < 4; ++j) {
            const int nb = n0 + colbase + j * 16 + quad * 4;
            float4 b4 = *(const float4*)&bias[nb];
            if (mode == 1) {
                float4 r;
                r.x = acc[i][j][0] + b4.x; r.y = acc[i][j][1] + b4.y;
                r.z = acc[i][j][2] + b4.z; r.w = acc[i][j][3] + b4.w;
                *(float4*)(outf + (size_t)m * ncols + nb) = r;
            } else {
                s4v r;
                r[0] = (short)f2bf(acc[i][j][0] + b4.x);
                r[1] = (short)f2bf(acc[i][j][1] + b4.y);
                r[2] = (short)f2bf(acc[i][j][2] + b4.z);
                r[3] = (short)f2bf(acc[i][j][3] + b4.w);
                *(s4v*)(outb + (size_t)m * ncols + nb) = r;
            }
        }
    }
}

// ---------------------------------------------------------------------------
// MFMA attention per (b,h) (unchanged from round 5/6).
// ---------------------------------------------------------------------------
#define PSTR 228

__global__ __launch_bounds__(256)
void attn_mfma(const unsigned short* __restrict__ qkv, unsigned short* __restrict__ attnbf)
{
    const int bh = blockIdx.x;
    const int b = bh / HH, h = bh - b * HH;
    const int tid = threadIdx.x;
    const int wave = tid >> 6, lane = tid & 63;
    const int quad = lane >> 4, l16 = lane & 15;
    __shared__ short Vs[64 * PSTR];        // V^T [dd][tok]
    __shared__ short Ps[4][16 * PSTR];     // per-wave P [query][key]

    const unsigned short* qg = qkv + (size_t)b * NTOK * 2304 + h * DH;
    const unsigned short* kg = qg + 768;
    const unsigned short* vg = qg + 1536;

    if (tid < NTOK) {
#pragma unroll
        for (int c = 0; c < 8; ++c) {
            s8v vv = *(const s8v*)(vg + (size_t)tid * 2304 + c * 8);
#pragma unroll
            for (int e = 0; e < 8; ++e) Vs[(c * 8 + e) * PSTR + tid] = vv[e];
        }
    }
    for (int f = tid; f < 64 * (PSTR - NTOK); f += 256) {
        int dd = f / (PSTR - NTOK);
        int tk = NTOK + (f - dd * (PSTR - NTOK));
        Vs[dd * PSTR + tk] = 0;
    }
    __syncthreads();

    for (int strip = wave; strip < 13; strip += 4) {
        const int mq = min(strip * 16 + l16, NTOK - 1);
        const s8v aq0 = *(const s8v*)(qg + (size_t)mq * 2304 + quad * 8);
        const s8v aq1 = *(const s8v*)(qg + (size_t)mq * 2304 + 32 + quad * 8);

        f4v sacc[14];
#pragma unroll
        for (int j = 0; j < 14; ++j) sacc[j] = (f4v)0.f;
#pragma unroll
        for (int j = 0; j < 14; ++j) {
            const int kt = min(j * 16 + l16, NTOK - 1);
            s8v bk0 = *(const s8v*)(kg + (size_t)kt * 2304 + quad * 8);
            s8v bk1 = *(const s8v*)(kg + (size_t)kt * 2304 + 32 + quad * 8);
            sacc[j] = __builtin_amdgcn_mfma_f32_16x16x32_bf16(bk0, aq0, sacc[j], 0, 0, 0);
            sacc[j] = __builtin_amdgcn_mfma_f32_16x16x32_bf16(bk1, aq1, sacc[j], 0, 0, 0);
        }

        float mx = -1e30f;
#pragma unroll
        for (int j = 0; j < 14; ++j)
#pragma unroll
            for (int r = 0; r < 4; ++r) {
                const int key = j * 16 + quad * 4 + r;
                float s = (key < NTOK) ? sacc[j][r] * 0.125f : -1e30f;
                sacc[j][r] = s;
                mx = fmaxf(mx, s);
            }
        mx = fmaxf(mx, __shfl_xor(mx, 16, 64));
        mx = fmaxf(mx, __shfl_xor(mx, 32, 64));

        float sm = 0.f;
#pragma unroll
        for (int j = 0; j < 14; ++j) {
            s4v pk;
#pragma unroll
            for (int r = 0; r < 4; ++r) {
                const int key = j * 16 + quad * 4 + r;
                float p = (key < NTOK) ? __expf(sacc[j][r] - mx) : 0.f;
                sm += p;
                pk[r] = (short)f2bf(p);
            }
            *(s4v*)&Ps[wave][l16 * PSTR + j * 16 + quad * 4] = pk;
        }
        sm += __shfl_xor(sm, 16, 64);
        sm += __shfl_xor(sm, 32, 64);
        const float rcp = 1.f / sm;

        f4v oacc[4];
#pragma unroll
        for (int j = 0; j < 4; ++j) oacc[j] = (f4v)0.f;
#pragma unroll
        for (int t = 0; t < 7; ++t) {
            const int ko = t * 32 + quad * 8;
            s8v ap = *(const s8v*)&Ps[wave][l16 * PSTR + ko];
#pragma unroll
            for (int j = 0; j < 4; ++j) {
                s8v bv = *(const s8v*)&Vs[(j * 16 + l16) * PSTR + ko];
                oacc[j] = __builtin_amdgcn_mfma_f32_16x16x32_bf16(bv, ap, oacc[j], 0, 0, 0);
            }
        }
        const int qrow = strip * 16 + l16;
        if (qrow < NTOK) {
#pragma unroll
            for (int j = 0; j < 4; ++j) {
                s4v o4;
#pragma unroll
                for (int r = 0; r < 4; ++r) o4[r] = (short)f2bf(oacc[j][r] * rcp);
                *(s4v*)&attnbf[((size_t)b * NTOK + qrow) * 768 + h * DH + j * 16 + quad * 4] = o4;
            }
        }
    }
}

// ---------------------------------------------------------------------------
// Exact fp32 cls path, fused per (b,h): q0h chain -> r chain (kept in LDS,
// bitwise-identical values) -> s chain. ASSOCIATION ORDER IS LOAD-BEARING
// (round-4 failure): every serial chain matches the round-5/6 passing code.
// Grid 1D id = h*64 + b so all h-blocks of a batch share an XCD (x reuse).
// ---------------------------------------------------------------------------
__global__ __launch_bounds__(256)
void qr_s(const float* __restrict__ x, const float* __restrict__ qkv_w,
          const float* __restrict__ qkv_b, float* __restrict__ sws)
{
    const int id = blockIdx.x;
    const int b = id & 63, h = id >> 6;
    const int tid = threadIdx.x;
    __shared__ float x0[CC];
    __shared__ float q0h[DH];
    __shared__ __align__(16) float rl[CC];
    __shared__ float bcs;

    for (int c = tid; c < CC; c += 256) x0[c] = x[(size_t)b * NTOK * CC + c];
    __syncthreads();
    if (tid < DH) {
        const int o = h * DH + tid;
        float acc = qkv_b[o];                       // identical q0 chain
        for (int c = 0; c < CC; ++c)
            acc = fmaf(x0[c], qkv_w[(size_t)c * 2304 + o], acc);
        q0h[tid] = acc;
    }
    __syncthreads();
    for (int c = tid; c < CC; c += 256) {           // identical r chain
        const float* wrow = qkv_w + (size_t)c * 2304 + CC + h * DH;
        float acc = 0.f;
#pragma unroll
        for (int d = 0; d < DH; d += 4) {
            float4 w4 = *(const float4*)(wrow + d);
            acc = fmaf(w4.x, q0h[d + 0], acc);
            acc = fmaf(w4.y, q0h[d + 1], acc);
            acc = fmaf(w4.z, q0h[d + 2], acc);
            acc = fmaf(w4.w, q0h[d + 3], acc);
        }
        rl[c] = acc;
    }
    if (tid == 0) {
        float acc = 0.f;
        for (int d = 0; d < DH; ++d) acc += q0h[d] * qkv_b[CC + h * DH + d];
        bcs = acc;
    }
    __syncthreads();
    if (tid < NTOK) {                               // identical s chain
        const float* xr = x + ((size_t)b * NTOK + tid) * CC;
        float acc = 0.f;
        for (int c = 0; c < CC; c += 4) {
            float4 r4 = *(const float4*)&rl[c];
            float4 x4 = *(const float4*)(xr + c);
            acc = fmaf(x4.x, r4.x, acc);
            acc = fmaf(x4.y, r4.y, acc);
            acc = fmaf(x4.z, r4.z, acc);
            acc = fmaf(x4.w, r4.w, acc);
        }
        sws[((size_t)b * HH + h) * NTOK + tid] = (acc + bcs) * 0.125f;
    }
}

// cls_topk: read s, then EXACT round-5/6 softmax/mean/bitonic/write code.
__global__ __launch_bounds__(256)
void cls_topk(const float* __restrict__ sws, float* __restrict__ out, int write_lt)
{
    const int b = blockIdx.x, tid = threadIdx.x;
    const int wave = tid >> 6, lane = tid & 63;
    __shared__ float sbuf[HH][208];
    __shared__ float pm[4][208];
    __shared__ float vals[256];
    __shared__ int   idxs[256];

    for (int jj = lane; jj < 208; jj += 64) pm[wave][jj] = 0.f;
    if (tid < NTOK) {
#pragma unroll
        for (int h = 0; h < HH; ++h)
            sbuf[h][tid] = sws[((size_t)b * HH + h) * NTOK + tid];
    }
    __syncthreads();

    for (int h = wave; h < HH; h += 4) {
        float sv[4], ev[4];
        float mx = -1e30f;
#pragma unroll
        for (int t = 0; t < 4; ++t) {
            int j = lane + 64 * t;
            sv[t] = (j < NTOK) ? sbuf[h][j] : -1e30f;
            mx = fmaxf(mx, sv[t]);
        }
#pragma unroll
        for (int off = 1; off < 64; off <<= 1) mx = fmaxf(mx, __shfl_xor(mx, off, 64));
        float sm = 0.f;
#pragma unroll
        for (int t = 0; t < 4; ++t) {
            int j = lane + 64 * t;
            ev[t] = (j < NTOK) ? expf(sv[t] - mx) : 0.f;
            sm += ev[t];
        }
#pragma unroll
        for (int off = 1; off < 64; off <<= 1) sm += __shfl_xor(sm, off, 64);
#pragma unroll
        for (int t = 0; t < 4; ++t) {
            int j = lane + 64 * t;
            if (j < NTOK) pm[wave][j] += ev[t] / sm;
        }
    }
    __syncthreads();

    float v = -INFINITY;
    int id = 256 + tid;
    if (tid < NTOK - 1) {
        int j = tid + 1;
        float s = ((pm[0][j] + pm[1][j]) + (pm[2][j] + pm[3][j])) * (1.f / 12.f);
        v = s; id = tid;
        out[CLS_OFF + (size_t)b * (NTOK - 1) + tid] = s;
    }
    vals[tid] = v; idxs[tid] = id;
    __syncthreads();

    for (int k = 2; k <= 256; k <<= 1) {
        for (int j = k >> 1; j > 0; j >>= 1) {
            int ixj = tid ^ j;
            if (ixj > tid) {
                float va = vals[tid], vb2 = vals[ixj];
                int ia = idxs[tid], ib = idxs[ixj];
                bool aLess = (va > vb2) || (va == vb2 && ia < ib);
                bool dir = ((tid & k) == 0);
                if (dir != aLess) {
                    vals[tid] = vb2; vals[ixj] = va;
                    idxs[tid] = ib;  idxs[ixj] = ia;
                }
            }
            __syncthreads();
        }
    }

    if (tid < LEFT) out[IDX_OFF + (size_t)b * LEFT + tid] = (float)idxs[tid];
    for (int u = tid; u < LEFT * CC; u += 256) {
        int t = u / CC;
        out[INDEX_OFF + (size_t)b * LEFT * CC + u] = (float)idxs[t];
    }
    if (write_lt && b == 0 && tid == 0) out[LT_OFF] = (float)LEFT;
}

// ---------------------------------------------------------------------------
extern "C" void kernel_launch(void* const* d_in, const int* in_sizes, int n_in,
                              void* d_out, int out_size, void* d_ws, size_t ws_size,
                              hipStream_t stream)
{
    const float* x      = (const float*)d_in[0];
    const float* qkv_w  = (const float*)d_in[1];
    const float* qkv_b  = (const float*)d_in[2];
    const float* proj_w = (const float*)d_in[3];
    const float* proj_b = (const float*)d_in[4];
    float* out = (float*)d_out;

    char* w = (char*)d_ws;
    unsigned short* xbf   = (unsigned short*)w; w += (size_t)MPAD * CC * 2;
    unsigned short* wt1   = (unsigned short*)w; w += (size_t)3 * CC * CC * 2;
    unsigned short* wt2   = (unsigned short*)w; w += (size_t)CC * CC * 2;
    unsigned short* qkvbf = (unsigned short*)w; w += (size_t)MTOT * 3 * CC * 2;
    unsigned short* atbf  = (unsigned short*)w; w += (size_t)MPAD * CC * 2;
    float* sws    = (float*)w; w += (size_t)BB * HH * NTOK * 4;

    prep<<<dim3(7032), 256, 0, stream>>>(x, qkv_w, proj_w, xbf, wt1, wt2);
    gemm_bf16<<<dim3(8 * 18 * 13), 256, 0, stream>>>(xbf, wt1, qkv_b, 18, 0, qkvbf, nullptr);
    attn_mfma<<<dim3(BB * HH), 256, 0, stream>>>(qkvbf, atbf);
    gemm_bf16<<<dim3(8 * 6 * 13), 256, 0, stream>>>(atbf, wt2, proj_b, 6, 1,
                                                    nullptr, out + XOUT_OFF);
    qr_s<<<dim3(BB * HH), 256, 0, stream>>>(x, qkv_w, qkv_b, sws);
    cls_topk<<<dim3(BB), 256, 0, stream>>>(sws, out, (out_size > LT_OFF) ? 1 : 0);
}